// Round 10
// baseline (136.457 us; speedup 1.0000x reference)
//
#include <hip/hip_runtime.h>
#include <math.h>

// B=32, HW=4096 (64x64), C=256, G=32, CG=8 -> 1024 samples of (8,64,64).
// r10: 512 persistent blocks (2/CU), 512 threads; each block processes
// samples n and n+512 sequentially. Sample-1 global reads are issued in the
// barrier-free window before apply(s0) so they overlap s0's stores.

#define NBLK 512
#define NTHR 512
#define CSTR 2052   // u32 per channel (4104 bf16 = 4096 px + pad)

typedef unsigned int uint;

__device__ __forceinline__ uint pk2(float a, float b) {   // 2x f32 -> packed bf16
    uint ua = __builtin_bit_cast(uint, a);
    uint ub = __builtin_bit_cast(uint, b);
    return ((ua + 0x8000u) >> 16) | ((ub + 0x8000u) & 0xFFFF0000u);
}
__device__ __forceinline__ float blo(uint u) { return __builtin_bit_cast(float, u << 16); }
__device__ __forceinline__ float bhi(uint u) { return __builtin_bit_cast(float, u & 0xFFFF0000u); }
__device__ __forceinline__ float sigm(float v) { return 1.0f / (1.0f + __expf(-v)); }

// ---- P1: load + pack one sample into the LDS tile (r5-proven) -------------
__device__ __forceinline__ void load_pack(const int t,
                                          const float4* __restrict__ x4,
                                          uint* __restrict__ tile)
{
#pragma unroll
    for (int k = 0; k < 8; ++k) {
        int idx = k * 512 + t;        // 0..4095
        int q = idx >> 1;             // pixel pair 0..2047
        int half = idx & 1;
        float4 va = x4[(size_t)q * 128 + half];        // px 2q
        float4 vb = x4[(size_t)q * 128 + 64 + half];   // px 2q+1
        int ch = half * 4;
        tile[(ch + 0) * CSTR + q] = pk2(va.x, vb.x);
        tile[(ch + 1) * CSTR + q] = pk2(va.y, vb.y);
        tile[(ch + 2) * CSTR + q] = pk2(va.z, vb.z);
        tile[(ch + 3) * CSTR + q] = pk2(va.w, vb.w);
    }
}

// ---- stats phases P2..P5c (r5/r9-proven math, 512-thread geometry) --------
__device__ __forceinline__ void stats_phases(
    const int t, const uint* __restrict__ tile,
    float* __restrict__ sg, float* __restrict__ t1s, float* __restrict__ weff,
    float* __restrict__ wconst, float* __restrict__ uni,
    float* Ti, float* m2s, float* Ai, float* Ci, float* x11s, float* x21s,
    const float* __restrict__ w1, const float* __restrict__ b1,
    const float* __restrict__ w3, const float* __restrict__ b3,
    const float* __restrict__ gn_w, const float* __restrict__ gn_b)
{
    float* Rs = uni;
    float* Cs = uni + 512;

    // P2: row/col sums + totals
    {
        const int i = t >> 6, l = t & 63, ys = l >> 3, xb = l & 7;
        float col[8] = {0, 0, 0, 0, 0, 0, 0, 0};
        float rowv[8];
#pragma unroll
        for (int r = 0; r < 8; ++r) {
            const uint4 d = *reinterpret_cast<const uint4*>(
                &tile[i * CSTR + (ys * 8 + r) * 32 + xb * 4]);
            float f0 = blo(d.x), f1 = bhi(d.x), f2 = blo(d.y), f3 = bhi(d.y);
            float f4 = blo(d.z), f5 = bhi(d.z), f6 = blo(d.w), f7 = bhi(d.w);
            rowv[r] = ((f0 + f1) + (f2 + f3)) + ((f4 + f5) + (f6 + f7));
            col[0] += f0; col[1] += f1; col[2] += f2; col[3] += f3;
            col[4] += f4; col[5] += f5; col[6] += f6; col[7] += f7;
        }
#pragma unroll
        for (int r = 0; r < 8; ++r) {
            float v = rowv[r];
            v += __shfl_xor(v, 1); v += __shfl_xor(v, 2); v += __shfl_xor(v, 4);
            if (xb == 0) Rs[i * 64 + ys * 8 + r] = v;
        }
        float tot = 0.f;
#pragma unroll
        for (int j = 0; j < 8; ++j) {
            float c = col[j];
            c += __shfl_xor(c, 8); c += __shfl_xor(c, 16); c += __shfl_xor(c, 32);
            if (ys == 0) Cs[i * 64 + xb * 8 + j] = c;
            tot += c;
        }
        tot += __shfl_xor(tot, 1); tot += __shfl_xor(tot, 2); tot += __shfl_xor(tot, 4);
        if (l == 0) Ti[i] = tot;
    }
    __syncthreads();

    // P3: gate matmul + sigmoid
    {
        const int o = t >> 6, p = t & 63;
        float vy = b1[o], vx = b1[o];
#pragma unroll
        for (int i = 0; i < 8; ++i) {
            float wv = w1[o * 8 + i] * (1.0f / 64.0f);
            vy += wv * Rs[i * 64 + p];
            vx += wv * Cs[i * 64 + p];
        }
        sg[o * 128 + p] = sigm(vy);
        sg[o * 128 + 64 + p] = sigm(vx);
    }
    __syncthreads();

    // P4: instance-norm stats (wave i = channel i)
    {
        const int i = t >> 6, l = t & 63, ys = l >> 3, xb = l & 7;
        const float4 sa = *reinterpret_cast<const float4*>(&sg[i * 128 + 64 + xb * 8]);
        const float4 sb = *reinterpret_cast<const float4*>(&sg[i * 128 + 64 + xb * 8 + 4]);
        float s = 0.f, s2 = 0.f;
#pragma unroll
        for (int r = 0; r < 8; ++r) {
            const float shv = sg[i * 128 + ys * 8 + r];
            const uint4 d = *reinterpret_cast<const uint4*>(
                &tile[i * CSTR + (ys * 8 + r) * 32 + xb * 4]);
            float g0 = blo(d.x) * shv * sa.x; s += g0; s2 += g0 * g0;
            float g1 = bhi(d.x) * shv * sa.y; s += g1; s2 += g1 * g1;
            float g2 = blo(d.y) * shv * sa.z; s += g2; s2 += g2 * g2;
            float g3 = bhi(d.y) * shv * sa.w; s += g3; s2 += g3 * g3;
            float g4 = blo(d.z) * shv * sb.x; s += g4; s2 += g4 * g4;
            float g5 = bhi(d.z) * shv * sb.y; s += g5; s2 += g5 * g5;
            float g6 = blo(d.w) * shv * sb.z; s += g6; s2 += g6 * g6;
            float g7 = bhi(d.w) * shv * sb.w; s += g7; s2 += g7 * g7;
        }
#pragma unroll
        for (int off = 32; off; off >>= 1) {
            s += __shfl_xor(s, off);
            s2 += __shfl_xor(s2, off);
        }
        if (l == 0) {
            float mu = s * (1.0f / 4096.0f);
            float var = s2 * (1.0f / 4096.0f) - mu * mu;
            float a = rsqrtf(var + 1e-5f) * gn_w[i];
            Ai[i] = a;
            Ci[i] = gn_b[i] - mu * a;
        }
    }
    // P5a: conv channel means via rectangle sums (wave 0)
    if (t < 64) {
        const int o = t >> 3, i = t & 7;
        const float T = Ti[i];
        float part = 0.f;
#pragma unroll
        for (int ky = 0; ky < 3; ++ky) {
            int dy = ky - 1;
#pragma unroll
            for (int kx = 0; kx < 3; ++kx) {
                int dx = kx - 1;
                float S = T;
                int er = (dy < 0) ? 63 : 0;
                int ec = (dx < 0) ? 63 : 0;
                if (dy != 0) S -= Rs[i * 64 + er];
                if (dx != 0) S -= Cs[i * 64 + ec];
                if (dy != 0 && dx != 0) {
                    uint u = tile[i * CSTR + er * 32 + (ec >> 1)];
                    S += (ec & 1) ? bhi(u) : blo(u);
                }
                part += w3[((o * 8 + i) * 3 + ky) * 3 + kx] * S;
            }
        }
        part += __shfl_xor(part, 1); part += __shfl_xor(part, 2); part += __shfl_xor(part, 4);
        if (i == 0) m2s[o] = part * (1.0f / 4096.0f) + b3[o];
    }
    // P5b: the two 8-way softmaxes (wave 0)
    if (t < 8) {
        float mx = m2s[0];
#pragma unroll
        for (int o = 1; o < 8; ++o) mx = fmaxf(mx, m2s[o]);
        float sum = 0.f;
#pragma unroll
        for (int o = 0; o < 8; ++o) sum += __expf(m2s[o] - mx);
        x21s[t] = __expf(m2s[t] - mx) / sum;
        // x1 spatial mean == gn_b exactly (normalized field)
        float mx1 = gn_b[0];
#pragma unroll
        for (int o = 1; o < 8; ++o) mx1 = fmaxf(mx1, gn_b[o]);
        float sum1 = 0.f;
#pragma unroll
        for (int o = 0; o < 8; ++o) sum1 += __expf(gn_b[o] - mx1);
        x11s[t] = __expf(gn_b[t] - mx1) / sum1;
    }
    __syncthreads();

    // P5c: collapsed filter (padded [8][12]), t1s, wconst
    if (t < 72) {
        const int i = t / 9, k = t % 9;
        float acc = 0.f;
#pragma unroll
        for (int o = 0; o < 8; ++o) acc += x11s[o] * w3[(o * 8 + i) * 9 + k];
        weff[i * 12 + (k / 3) * 4 + (k % 3)] = acc;
    }
    {
        const int i = t >> 6, y = t & 63;
        t1s[i * 64 + y] = x21s[i] * Ai[i] * sg[i * 128 + y];
    }
    if (t == 0) {
        float wc = 0.f;
#pragma unroll
        for (int o = 0; o < 8; ++o) wc += x11s[o] * b3[o] + x21s[o] * Ci[o];
        *wconst = wc;
    }
}

// ---- P6: per-pixel weight + sigmoid + store (barrier-free) ----------------
// Re-reads center rows from LDS after sigmoid (no gla[8] held -> low VGPR).
__device__ __forceinline__ void apply_store(
    const int t, const uint* __restrict__ tile, const float* __restrict__ sg,
    const float* __restrict__ t1s, const float* __restrict__ weff,
    const float wconst, float4* __restrict__ out4)
{
    const int y = t >> 3, xb = t & 7;      // 8 consecutive px per thread
    float ws0 = wconst, ws1 = wconst, ws2 = wconst, ws3 = wconst;
    float ws4 = wconst, ws5 = wconst, ws6 = wconst, ws7 = wconst;
#pragma unroll
    for (int i = 0; i < 8; ++i) {
        const float t1v = t1s[i * 64 + y];
        const float4 sa = *reinterpret_cast<const float4*>(&sg[i * 128 + 64 + xb * 8]);
        const float4 sb = *reinterpret_cast<const float4*>(&sg[i * 128 + 64 + xb * 8 + 4]);
#pragma unroll
        for (int dy = -1; dy <= 1; ++dy) {
            const int yy = y + dy;
            if (yy < 0 || yy > 63) continue;   // diverges only in first/last y-octet
            const uint4 d = *reinterpret_cast<const uint4*>(
                &tile[i * CSTR + yy * 32 + xb * 4]);
            float f0 = blo(d.x), f1 = bhi(d.x), f2 = blo(d.y), f3 = bhi(d.y);
            float f4 = blo(d.z), f5 = bhi(d.z), f6 = blo(d.w), f7 = bhi(d.w);
            float vm = __shfl_up(f7, 1);       // prev lane's last px (same row)
            float vp = __shfl_down(f0, 1);     // next lane's first px
            vm = (xb == 0) ? 0.f : vm;
            vp = (xb == 7) ? 0.f : vp;
            const float4 wv = *reinterpret_cast<const float4*>(&weff[i * 12 + (dy + 1) * 4]);
            const float wl = wv.x, wc = wv.y, wr = wv.z;
            ws0 += wl * vm + wc * f0 + wr * f1;
            ws1 += wl * f0 + wc * f1 + wr * f2;
            ws2 += wl * f1 + wc * f2 + wr * f3;
            ws3 += wl * f2 + wc * f3 + wr * f4;
            ws4 += wl * f3 + wc * f4 + wr * f5;
            ws5 += wl * f4 + wc * f5 + wr * f6;
            ws6 += wl * f5 + wc * f6 + wr * f7;
            ws7 += wl * f6 + wc * f7 + wr * vp;
            if (dy == 0) {
                ws0 += t1v * sa.x * f0;  ws1 += t1v * sa.y * f1;
                ws2 += t1v * sa.z * f2;  ws3 += t1v * sa.w * f3;
                ws4 += t1v * sb.x * f4;  ws5 += t1v * sb.y * f5;
                ws6 += t1v * sb.z * f6;  ws7 += t1v * sb.w * f7;
            }
        }
    }
    const float s0 = sigm(ws0), s1 = sigm(ws1), s2 = sigm(ws2), s3 = sigm(ws3);
    const float s4 = sigm(ws4), s5 = sigm(ws5), s6 = sigm(ws6), s7 = sigm(ws7);
    const size_t pb = (size_t)(y * 64 + xb * 8) * 64;
    // lo half: channels 0..3 (re-read center rows, 16 VGPR transient)
    {
        uint4 c0 = *reinterpret_cast<const uint4*>(&tile[0 * CSTR + y * 32 + xb * 4]);
        uint4 c1 = *reinterpret_cast<const uint4*>(&tile[1 * CSTR + y * 32 + xb * 4]);
        uint4 c2 = *reinterpret_cast<const uint4*>(&tile[2 * CSTR + y * 32 + xb * 4]);
        uint4 c3 = *reinterpret_cast<const uint4*>(&tile[3 * CSTR + y * 32 + xb * 4]);
        float4 v;
        v.x = blo(c0.x) * s0; v.y = blo(c1.x) * s0; v.z = blo(c2.x) * s0; v.w = blo(c3.x) * s0;
        out4[pb + 0] = v;
        v.x = bhi(c0.x) * s1; v.y = bhi(c1.x) * s1; v.z = bhi(c2.x) * s1; v.w = bhi(c3.x) * s1;
        out4[pb + 64] = v;
        v.x = blo(c0.y) * s2; v.y = blo(c1.y) * s2; v.z = blo(c2.y) * s2; v.w = blo(c3.y) * s2;
        out4[pb + 128] = v;
        v.x = bhi(c0.y) * s3; v.y = bhi(c1.y) * s3; v.z = bhi(c2.y) * s3; v.w = bhi(c3.y) * s3;
        out4[pb + 192] = v;
        v.x = blo(c0.z) * s4; v.y = blo(c1.z) * s4; v.z = blo(c2.z) * s4; v.w = blo(c3.z) * s4;
        out4[pb + 256] = v;
        v.x = bhi(c0.z) * s5; v.y = bhi(c1.z) * s5; v.z = bhi(c2.z) * s5; v.w = bhi(c3.z) * s5;
        out4[pb + 320] = v;
        v.x = blo(c0.w) * s6; v.y = blo(c1.w) * s6; v.z = blo(c2.w) * s6; v.w = blo(c3.w) * s6;
        out4[pb + 384] = v;
        v.x = bhi(c0.w) * s7; v.y = bhi(c1.w) * s7; v.z = bhi(c2.w) * s7; v.w = bhi(c3.w) * s7;
        out4[pb + 448] = v;
    }
    // hi half: channels 4..7
    {
        uint4 c4 = *reinterpret_cast<const uint4*>(&tile[4 * CSTR + y * 32 + xb * 4]);
        uint4 c5 = *reinterpret_cast<const uint4*>(&tile[5 * CSTR + y * 32 + xb * 4]);
        uint4 c6 = *reinterpret_cast<const uint4*>(&tile[6 * CSTR + y * 32 + xb * 4]);
        uint4 c7 = *reinterpret_cast<const uint4*>(&tile[7 * CSTR + y * 32 + xb * 4]);
        float4 v;
        v.x = blo(c4.x) * s0; v.y = blo(c5.x) * s0; v.z = blo(c6.x) * s0; v.w = blo(c7.x) * s0;
        out4[pb + 1] = v;
        v.x = bhi(c4.x) * s1; v.y = bhi(c5.x) * s1; v.z = bhi(c6.x) * s1; v.w = bhi(c7.x) * s1;
        out4[pb + 65] = v;
        v.x = blo(c4.y) * s2; v.y = blo(c5.y) * s2; v.z = blo(c6.y) * s2; v.w = blo(c7.y) * s2;
        out4[pb + 129] = v;
        v.x = bhi(c4.y) * s3; v.y = bhi(c5.y) * s3; v.z = bhi(c6.y) * s3; v.w = bhi(c7.y) * s3;
        out4[pb + 193] = v;
        v.x = blo(c4.z) * s4; v.y = blo(c5.z) * s4; v.z = blo(c6.z) * s4; v.w = blo(c7.z) * s4;
        out4[pb + 257] = v;
        v.x = bhi(c4.z) * s5; v.y = bhi(c5.z) * s5; v.z = bhi(c6.z) * s5; v.w = bhi(c7.z) * s5;
        out4[pb + 321] = v;
        v.x = blo(c4.w) * s6; v.y = blo(c5.w) * s6; v.z = blo(c6.w) * s6; v.w = blo(c7.w) * s6;
        out4[pb + 385] = v;
        v.x = bhi(c4.w) * s7; v.y = bhi(c5.w) * s7; v.z = bhi(c6.w) * s7; v.w = bhi(c7.w) * s7;
        out4[pb + 449] = v;
    }
}

__global__ __launch_bounds__(512, 4) void fused_ema_pipe_kernel(
    const float* __restrict__ x,     // (32, 4096, 256)
    const float* __restrict__ w1, const float* __restrict__ b1,
    const float* __restrict__ w3, const float* __restrict__ b3,
    const float* __restrict__ gn_w, const float* __restrict__ gn_b,
    float* __restrict__ out)
{
    __shared__ __align__(16) uint  tile[8 * CSTR];   // 65,664 B bf16-pair gx
    __shared__ __align__(16) float sg[1024];
    __shared__ __align__(16) float uni[1024];
    __shared__ __align__(16) float t1s[512];
    __shared__ __align__(16) float weff[96];
    __shared__ float Ti[8], m2s[8], Ai[8], Ci[8], x11s[8], x21s[8];
    __shared__ float wcs;

    const int t = threadIdx.x;
    const int bi = blockIdx.x;
    // quad-swizzle over the 512 first-half samples (b 0..15); s1 = +512.
    const int n0 = ((bi & 7) * 16 + ((bi >> 3) >> 2)) * 4 + ((bi >> 3) & 3);
    const int b0 = n0 >> 5, g0 = n0 & 31;
    const int b1v = b0 + 16;

    const float4* x40 = reinterpret_cast<const float4*>(x) + (size_t)b0 * 4096 * 64 + g0 * 2;
    const float4* x41 = reinterpret_cast<const float4*>(x) + (size_t)b1v * 4096 * 64 + g0 * 2;
    float4* out40 = reinterpret_cast<float4*>(out) + (size_t)b0 * 4096 * 64 + g0 * 2;
    float4* out41 = reinterpret_cast<float4*>(out) + (size_t)b1v * 4096 * 64 + g0 * 2;

    // ---- sample 0 ----------------------------------------------------------
    load_pack(t, x40, tile);
    __syncthreads();
    stats_phases(t, tile, sg, t1s, weff, &wcs, uni,
                 Ti, m2s, Ai, Ci, x11s, x21s, w1, b1, w3, b3, gn_w, gn_b);
    __syncthreads();

    // ---- prefetch sample 1 in the barrier-free window ----------------------
    float4 va[8], vb[8];
#pragma unroll
    for (int k = 0; k < 8; ++k) {
        int idx = k * 512 + t;
        int q = idx >> 1;
        int half = idx & 1;
        va[k] = x41[(size_t)q * 128 + half];
        vb[k] = x41[(size_t)q * 128 + 64 + half];
    }
    __builtin_amdgcn_sched_barrier(0);   // loads issue before apply

    // ---- apply(s0): no barriers inside; s1 reads overlap s0 stores ---------
    apply_store(t, tile, sg, t1s, weff, wcs, out40);
    __syncthreads();   // waits s1 loads (long since landed) + drains stores

    // ---- pack s1 into tile --------------------------------------------------
#pragma unroll
    for (int k = 0; k < 8; ++k) {
        int idx = k * 512 + t;
        int q = idx >> 1;
        int half = idx & 1;
        int ch = half * 4;
        tile[(ch + 0) * CSTR + q] = pk2(va[k].x, vb[k].x);
        tile[(ch + 1) * CSTR + q] = pk2(va[k].y, vb[k].y);
        tile[(ch + 2) * CSTR + q] = pk2(va[k].z, vb[k].z);
        tile[(ch + 3) * CSTR + q] = pk2(va[k].w, vb[k].w);
    }
    __syncthreads();

    // ---- sample 1 ----------------------------------------------------------
    stats_phases(t, tile, sg, t1s, weff, &wcs, uni,
                 Ti, m2s, Ai, Ci, x11s, x21s, w1, b1, w3, b3, gn_w, gn_b);
    __syncthreads();
    apply_store(t, tile, sg, t1s, weff, wcs, out41);
}

extern "C" void kernel_launch(void* const* d_in, const int* in_sizes, int n_in,
                              void* d_out, int out_size, void* d_ws, size_t ws_size,
                              hipStream_t stream) {
    const float* x    = (const float*)d_in[0];
    const float* w1   = (const float*)d_in[1];
    const float* b1   = (const float*)d_in[2];
    const float* w3   = (const float*)d_in[3];
    const float* b3   = (const float*)d_in[4];
    const float* gn_w = (const float*)d_in[5];
    const float* gn_b = (const float*)d_in[6];
    float* out = (float*)d_out;

    hipLaunchKernelGGL(fused_ema_pipe_kernel, dim3(NBLK), dim3(NTHR), 0, stream,
                       x, w1, b1, w3, b3, gn_w, gn_b, out);
}

// Round 11
// 123.057 us; speedup vs baseline: 1.1089x; 1.1089x over previous
//
#include <hip/hip_runtime.h>
#include <math.h>

// B=32, HW=4096 (64x64), C=256, G=32, CG=8 -> 1024 samples of (8,64,64).
// r11: one workgroup per sample, 1024 threads (16 waves) x 2 blocks/CU
// = 32 waves/CU (full cap). Memory phases (P1 load, P6 apply) use all 16
// waves; stats phases keep the proven r5 512-thread geometry (t<512).
// Lean P6 (4 px/thread, ctr held as uint2[8]) keeps VGPR <= 64.

#define NBLK 1024
#define NTHR 1024
#define CSTR 2052   // u32 per channel (4104 bf16 = 4096 px + pad)

typedef unsigned int uint;

__device__ __forceinline__ uint pk2(float a, float b) {   // 2x f32 -> packed bf16
    uint ua = __builtin_bit_cast(uint, a);
    uint ub = __builtin_bit_cast(uint, b);
    return ((ua + 0x8000u) >> 16) | ((ub + 0x8000u) & 0xFFFF0000u);
}
__device__ __forceinline__ float blo(uint u) { return __builtin_bit_cast(float, u << 16); }
__device__ __forceinline__ float bhi(uint u) { return __builtin_bit_cast(float, u & 0xFFFF0000u); }
__device__ __forceinline__ float sigm(float v) { return 1.0f / (1.0f + __expf(-v)); }

__global__ __launch_bounds__(1024, 8) void fused_ema_kernel(
    const float* __restrict__ x,     // (32, 4096, 256)
    const float* __restrict__ w1,    // (8,8)
    const float* __restrict__ b1,    // (8)
    const float* __restrict__ w3,    // (8,8,3,3)
    const float* __restrict__ b3,    // (8)
    const float* __restrict__ gn_w,  // (8)
    const float* __restrict__ gn_b,  // (8)
    float* __restrict__ out)         // (32, 4096, 256)
{
    __shared__ __align__(16) uint  gxp[8 * CSTR];   // 65,664 B: bf16-pair gx [i][y][x]
    __shared__ __align__(16) float sg[1024];        // [:64]=sh(y), [64:]=sw(x) per ch
    __shared__ __align__(16) float uni[1024];       // Rs [0:512) | Cs [512:1024)
    __shared__ __align__(16) float t1s[512];        // x21*Ai*sh[y]
    __shared__ __align__(16) float weff[96];        // [8][12] padded collapsed filter
    __shared__ float Ti[8], m2s[8], Ai[8], Ci[8], x11s[8], x21s[8];
    __shared__ float wconst_s;

    const int t = threadIdx.x;
    // quad (same b, 4 consecutive g sharing each 128B line) -> same XCD, close slots
    const int bi = blockIdx.x;
    const int n = ((bi & 7) * 32 + ((bi >> 3) >> 2)) * 4 + ((bi >> 3) & 3);
    const int b = n >> 5;
    const int g = n & 31;

    // ---------------- Phase 1: load x -> LDS (bf16 pairs), 16 waves ---------
    {
        const float4* x4 = reinterpret_cast<const float4*>(x) + (size_t)b * 4096 * 64 + g * 2;
#pragma unroll
        for (int k = 0; k < 4; ++k) {
            int idx = k * 1024 + t;       // 0..4095
            int q = idx >> 1;             // pixel pair 0..2047
            int half = idx & 1;
            float4 va = x4[(size_t)q * 128 + half];        // px 2q
            float4 vb = x4[(size_t)q * 128 + 64 + half];   // px 2q+1
            int ch = half * 4;
            gxp[(ch + 0) * CSTR + q] = pk2(va.x, vb.x);
            gxp[(ch + 1) * CSTR + q] = pk2(va.y, vb.y);
            gxp[(ch + 2) * CSTR + q] = pk2(va.z, vb.z);
            gxp[(ch + 3) * CSTR + q] = pk2(va.w, vb.w);
        }
    }
    __syncthreads();

    float* Rs = uni;          // [8][64] row sums (over x)
    float* Cs = uni + 512;    // [8][64] col sums (over y)

    // ---------------- Phase 2: Rs/Cs/Ti via b128 + shfl (t<512) -------------
    if (t < 512) {
        const int i = t >> 6, l = t & 63, ys = l >> 3, xb = l & 7;
        float col[8] = {0, 0, 0, 0, 0, 0, 0, 0};
        float rowv[8];
#pragma unroll
        for (int r = 0; r < 8; ++r) {
            const uint4 d = *reinterpret_cast<const uint4*>(
                &gxp[i * CSTR + (ys * 8 + r) * 32 + xb * 4]);
            float f0 = blo(d.x), f1 = bhi(d.x), f2 = blo(d.y), f3 = bhi(d.y);
            float f4 = blo(d.z), f5 = bhi(d.z), f6 = blo(d.w), f7 = bhi(d.w);
            rowv[r] = ((f0 + f1) + (f2 + f3)) + ((f4 + f5) + (f6 + f7));
            col[0] += f0; col[1] += f1; col[2] += f2; col[3] += f3;
            col[4] += f4; col[5] += f5; col[6] += f6; col[7] += f7;
        }
#pragma unroll
        for (int r = 0; r < 8; ++r) {
            float v = rowv[r];
            v += __shfl_xor(v, 1); v += __shfl_xor(v, 2); v += __shfl_xor(v, 4);
            if (xb == 0) Rs[i * 64 + ys * 8 + r] = v;
        }
        float tot = 0.f;
#pragma unroll
        for (int j = 0; j < 8; ++j) {
            float c = col[j];
            c += __shfl_xor(c, 8); c += __shfl_xor(c, 16); c += __shfl_xor(c, 32);
            if (ys == 0) Cs[i * 64 + xb * 8 + j] = c;
            tot += c;
        }
        tot += __shfl_xor(tot, 1); tot += __shfl_xor(tot, 2); tot += __shfl_xor(tot, 4);
        if (l == 0) Ti[i] = tot;
    }
    __syncthreads();

    // ---------------- Phase 3: gate matmul (8x8) + sigmoid (t<512) ----------
    if (t < 512) {
        const int o = t >> 6, p = t & 63;
        float vy = b1[o], vx = b1[o];
#pragma unroll
        for (int i = 0; i < 8; ++i) {
            float wv = w1[o * 8 + i] * (1.0f / 64.0f);
            vy += wv * Rs[i * 64 + p];
            vx += wv * Cs[i * 64 + p];
        }
        sg[o * 128 + p] = sigm(vy);
        sg[o * 128 + 64 + p] = sigm(vx);
    }
    __syncthreads();

    // ---------------- Phase 4: instance-norm stats (t<512) ------------------
    if (t < 512) {
        const int i = t >> 6, l = t & 63, ys = l >> 3, xb = l & 7;
        const float4 sa = *reinterpret_cast<const float4*>(&sg[i * 128 + 64 + xb * 8]);
        const float4 sb = *reinterpret_cast<const float4*>(&sg[i * 128 + 64 + xb * 8 + 4]);
        float s = 0.f, s2 = 0.f;
#pragma unroll
        for (int r = 0; r < 8; ++r) {
            const float shv = sg[i * 128 + ys * 8 + r];
            const uint4 d = *reinterpret_cast<const uint4*>(
                &gxp[i * CSTR + (ys * 8 + r) * 32 + xb * 4]);
            float g0 = blo(d.x) * shv * sa.x; s += g0; s2 += g0 * g0;
            float g1 = bhi(d.x) * shv * sa.y; s += g1; s2 += g1 * g1;
            float g2 = blo(d.y) * shv * sa.z; s += g2; s2 += g2 * g2;
            float g3 = bhi(d.y) * shv * sa.w; s += g3; s2 += g3 * g3;
            float g4 = blo(d.z) * shv * sb.x; s += g4; s2 += g4 * g4;
            float g5 = bhi(d.z) * shv * sb.y; s += g5; s2 += g5 * g5;
            float g6 = blo(d.w) * shv * sb.z; s += g6; s2 += g6 * g6;
            float g7 = bhi(d.w) * shv * sb.w; s += g7; s2 += g7 * g7;
        }
#pragma unroll
        for (int off = 32; off; off >>= 1) {
            s += __shfl_xor(s, off);
            s2 += __shfl_xor(s2, off);
        }
        if (l == 0) {
            float mu = s * (1.0f / 4096.0f);
            float var = s2 * (1.0f / 4096.0f) - mu * mu;
            float a = rsqrtf(var + 1e-5f) * gn_w[i];
            Ai[i] = a;
            Ci[i] = gn_b[i] - mu * a;
        }
    }
    // ---- Phase 5a: conv channel means from rectangle sums (wave 0) ---------
    if (t < 64) {
        const int o = t >> 3, i = t & 7;
        const float T = Ti[i];
        float part = 0.f;
#pragma unroll
        for (int ky = 0; ky < 3; ++ky) {
            int dy = ky - 1;
#pragma unroll
            for (int kx = 0; kx < 3; ++kx) {
                int dx = kx - 1;
                float S = T;
                int er = (dy < 0) ? 63 : 0;
                int ec = (dx < 0) ? 63 : 0;
                if (dy != 0) S -= Rs[i * 64 + er];
                if (dx != 0) S -= Cs[i * 64 + ec];
                if (dy != 0 && dx != 0) {
                    uint u = gxp[i * CSTR + er * 32 + (ec >> 1)];
                    S += (ec & 1) ? bhi(u) : blo(u);
                }
                part += w3[((o * 8 + i) * 3 + ky) * 3 + kx] * S;
            }
        }
        part += __shfl_xor(part, 1); part += __shfl_xor(part, 2); part += __shfl_xor(part, 4);
        if (i == 0) m2s[o] = part * (1.0f / 4096.0f) + b3[o];
    }
    // ---- Phase 5b: the two 8-way softmaxes (same wave as 5a writers) -------
    if (t < 8) {
        float mx = m2s[0];
#pragma unroll
        for (int o = 1; o < 8; ++o) mx = fmaxf(mx, m2s[o]);
        float sum = 0.f;
#pragma unroll
        for (int o = 0; o < 8; ++o) sum += __expf(m2s[o] - mx);
        x21s[t] = __expf(m2s[t] - mx) / sum;
        // x1 spatial mean == gn_b exactly (normalized field)
        float mx1 = gn_b[0];
#pragma unroll
        for (int o = 1; o < 8; ++o) mx1 = fmaxf(mx1, gn_b[o]);
        float sum1 = 0.f;
#pragma unroll
        for (int o = 0; o < 8; ++o) sum1 += __expf(gn_b[o] - mx1);
        x11s[t] = __expf(gn_b[t] - mx1) / sum1;
    }
    __syncthreads();

    // ---- Phase 5c: collapsed filter (padded [8][12]), t1, constants --------
    if (t < 72) {
        const int i = t / 9, k = t % 9;
        float acc = 0.f;
#pragma unroll
        for (int o = 0; o < 8; ++o) acc += x11s[o] * w3[(o * 8 + i) * 9 + k];
        weff[i * 12 + (k / 3) * 4 + (k % 3)] = acc;
    }
    if (t < 512) {
        const int i = t >> 6, y = t & 63;
        t1s[i * 64 + y] = x21s[i] * Ai[i] * sg[i * 128 + y];
    }
    if (t == 0) {
        float wc = 0.f;
#pragma unroll
        for (int o = 0; o < 8; ++o) wc += x11s[o] * b3[o] + x21s[o] * Ci[o];
        wconst_s = wc;
    }
    __syncthreads();

    // ---- Phase 6: per-pixel weight, sigmoid, output (16 waves, 4 px) -------
    {
        const int y = t >> 4, xq = t & 15;      // 4 consecutive px per thread
        float ws0 = wconst_s, ws1 = wconst_s, ws2 = wconst_s, ws3 = wconst_s;
        uint2 ctr[8];
#pragma unroll
        for (int i = 0; i < 8; ++i) {
            const float t1v = t1s[i * 64 + y];
            const float4 sa = *reinterpret_cast<const float4*>(&sg[i * 128 + 64 + xq * 4]);
#pragma unroll
            for (int dy = -1; dy <= 1; ++dy) {
                const int yy = y + dy;
                if (yy < 0 || yy > 63) continue;   // wave-uniform (y uniform per 16 lanes? no: per-lane guarded, edges masked consistently with shfl use)
                const uint2 d = *reinterpret_cast<const uint2*>(
                    &gxp[i * CSTR + yy * 32 + xq * 2]);
                float f0 = blo(d.x), f1 = bhi(d.x), f2 = blo(d.y), f3 = bhi(d.y);
                float vm = __shfl_up(f3, 1);       // prev lane's last px (same row)
                float vp = __shfl_down(f0, 1);     // next lane's first px
                vm = (xq == 0) ? 0.f : vm;
                vp = (xq == 15) ? 0.f : vp;
                const float4 wv = *reinterpret_cast<const float4*>(&weff[i * 12 + (dy + 1) * 4]);
                ws0 += wv.x * vm + wv.y * f0 + wv.z * f1;
                ws1 += wv.x * f0 + wv.y * f1 + wv.z * f2;
                ws2 += wv.x * f1 + wv.y * f2 + wv.z * f3;
                ws3 += wv.x * f2 + wv.y * f3 + wv.z * vp;
                if (dy == 0) {
                    ctr[i] = d;
                    ws0 += t1v * sa.x * f0;
                    ws1 += t1v * sa.y * f1;
                    ws2 += t1v * sa.z * f2;
                    ws3 += t1v * sa.w * f3;
                }
            }
        }
        const float s0 = sigm(ws0), s1 = sigm(ws1), s2 = sigm(ws2), s3 = sigm(ws3);
        float4* out4 = reinterpret_cast<float4*>(out) + (size_t)b * 4096 * 64 + g * 2;
        const size_t p0 = (size_t)(y * 64 + xq * 4) * 64;
        float4 u, w;
        u.x = blo(ctr[0].x) * s0; u.y = blo(ctr[1].x) * s0; u.z = blo(ctr[2].x) * s0; u.w = blo(ctr[3].x) * s0;
        w.x = blo(ctr[4].x) * s0; w.y = blo(ctr[5].x) * s0; w.z = blo(ctr[6].x) * s0; w.w = blo(ctr[7].x) * s0;
        out4[p0 + 0] = u; out4[p0 + 1] = w;
        u.x = bhi(ctr[0].x) * s1; u.y = bhi(ctr[1].x) * s1; u.z = bhi(ctr[2].x) * s1; u.w = bhi(ctr[3].x) * s1;
        w.x = bhi(ctr[4].x) * s1; w.y = bhi(ctr[5].x) * s1; w.z = bhi(ctr[6].x) * s1; w.w = bhi(ctr[7].x) * s1;
        out4[p0 + 64] = u; out4[p0 + 65] = w;
        u.x = blo(ctr[0].y) * s2; u.y = blo(ctr[1].y) * s2; u.z = blo(ctr[2].y) * s2; u.w = blo(ctr[3].y) * s2;
        w.x = blo(ctr[4].y) * s2; w.y = blo(ctr[5].y) * s2; w.z = blo(ctr[6].y) * s2; w.w = blo(ctr[7].y) * s2;
        out4[p0 + 128] = u; out4[p0 + 129] = w;
        u.x = bhi(ctr[0].y) * s3; u.y = bhi(ctr[1].y) * s3; u.z = bhi(ctr[2].y) * s3; u.w = bhi(ctr[3].y) * s3;
        w.x = bhi(ctr[4].y) * s3; w.y = bhi(ctr[5].y) * s3; w.z = bhi(ctr[6].y) * s3; w.w = bhi(ctr[7].y) * s3;
        out4[p0 + 192] = u; out4[p0 + 193] = w;
    }
}

extern "C" void kernel_launch(void* const* d_in, const int* in_sizes, int n_in,
                              void* d_out, int out_size, void* d_ws, size_t ws_size,
                              hipStream_t stream) {
    const float* x    = (const float*)d_in[0];
    const float* w1   = (const float*)d_in[1];
    const float* b1   = (const float*)d_in[2];
    const float* w3   = (const float*)d_in[3];
    const float* b3   = (const float*)d_in[4];
    const float* gn_w = (const float*)d_in[5];
    const float* gn_b = (const float*)d_in[6];
    float* out = (float*)d_out;

    hipLaunchKernelGGL(fused_ema_kernel, dim3(NBLK), dim3(NTHR), 0, stream,
                       x, w1, b1, w3, b3, gn_w, gn_b, out);
}

// Round 12
// 103.110 us; speedup vs baseline: 1.3234x; 1.1935x over previous
//
#include <hip/hip_runtime.h>
#include <math.h>

// B=32, HW=4096 (64x64), C=256, G=32, CG=8 -> 1024 samples of (8,64,64).
// r12: one workgroup per sample, 1024 threads (16 waves) x 2 blocks/CU
// = 32 waves/CU. Identical to r11 except __launch_bounds__(1024, 4):
// gives the allocator a 128-VGPR budget (natural alloc ~56, no spills);
// at <=64 actual VGPRs the HW still fits 2 blocks/CU (LDS-bound).

#define NBLK 1024
#define NTHR 1024
#define CSTR 2052   // u32 per channel (4104 bf16 = 4096 px + pad)

typedef unsigned int uint;

__device__ __forceinline__ uint pk2(float a, float b) {   // 2x f32 -> packed bf16
    uint ua = __builtin_bit_cast(uint, a);
    uint ub = __builtin_bit_cast(uint, b);
    return ((ua + 0x8000u) >> 16) | ((ub + 0x8000u) & 0xFFFF0000u);
}
__device__ __forceinline__ float blo(uint u) { return __builtin_bit_cast(float, u << 16); }
__device__ __forceinline__ float bhi(uint u) { return __builtin_bit_cast(float, u & 0xFFFF0000u); }
__device__ __forceinline__ float sigm(float v) { return 1.0f / (1.0f + __expf(-v)); }

__global__ __launch_bounds__(1024, 4) void fused_ema_kernel(
    const float* __restrict__ x,     // (32, 4096, 256)
    const float* __restrict__ w1,    // (8,8)
    const float* __restrict__ b1,    // (8)
    const float* __restrict__ w3,    // (8,8,3,3)
    const float* __restrict__ b3,    // (8)
    const float* __restrict__ gn_w,  // (8)
    const float* __restrict__ gn_b,  // (8)
    float* __restrict__ out)         // (32, 4096, 256)
{
    __shared__ __align__(16) uint  gxp[8 * CSTR];   // 65,664 B: bf16-pair gx [i][y][x]
    __shared__ __align__(16) float sg[1024];        // [:64]=sh(y), [64:]=sw(x) per ch
    __shared__ __align__(16) float uni[1024];       // Rs [0:512) | Cs [512:1024)
    __shared__ __align__(16) float t1s[512];        // x21*Ai*sh[y]
    __shared__ __align__(16) float weff[96];        // [8][12] padded collapsed filter
    __shared__ float Ti[8], m2s[8], Ai[8], Ci[8], x11s[8], x21s[8];
    __shared__ float wconst_s;

    const int t = threadIdx.x;
    // quad (same b, 4 consecutive g sharing each 128B line) -> same XCD, close slots
    const int bi = blockIdx.x;
    const int n = ((bi & 7) * 32 + ((bi >> 3) >> 2)) * 4 + ((bi >> 3) & 3);
    const int b = n >> 5;
    const int g = n & 31;

    // ---------------- Phase 1: load x -> LDS (bf16 pairs), 16 waves ---------
    {
        const float4* x4 = reinterpret_cast<const float4*>(x) + (size_t)b * 4096 * 64 + g * 2;
#pragma unroll
        for (int k = 0; k < 4; ++k) {
            int idx = k * 1024 + t;       // 0..4095
            int q = idx >> 1;             // pixel pair 0..2047
            int half = idx & 1;
            float4 va = x4[(size_t)q * 128 + half];        // px 2q
            float4 vb = x4[(size_t)q * 128 + 64 + half];   // px 2q+1
            int ch = half * 4;
            gxp[(ch + 0) * CSTR + q] = pk2(va.x, vb.x);
            gxp[(ch + 1) * CSTR + q] = pk2(va.y, vb.y);
            gxp[(ch + 2) * CSTR + q] = pk2(va.z, vb.z);
            gxp[(ch + 3) * CSTR + q] = pk2(va.w, vb.w);
        }
    }
    __syncthreads();

    float* Rs = uni;          // [8][64] row sums (over x)
    float* Cs = uni + 512;    // [8][64] col sums (over y)

    // ---------------- Phase 2: Rs/Cs/Ti via b128 + shfl (t<512) -------------
    if (t < 512) {
        const int i = t >> 6, l = t & 63, ys = l >> 3, xb = l & 7;
        float col[8] = {0, 0, 0, 0, 0, 0, 0, 0};
        float rowv[8];
#pragma unroll
        for (int r = 0; r < 8; ++r) {
            const uint4 d = *reinterpret_cast<const uint4*>(
                &gxp[i * CSTR + (ys * 8 + r) * 32 + xb * 4]);
            float f0 = blo(d.x), f1 = bhi(d.x), f2 = blo(d.y), f3 = bhi(d.y);
            float f4 = blo(d.z), f5 = bhi(d.z), f6 = blo(d.w), f7 = bhi(d.w);
            rowv[r] = ((f0 + f1) + (f2 + f3)) + ((f4 + f5) + (f6 + f7));
            col[0] += f0; col[1] += f1; col[2] += f2; col[3] += f3;
            col[4] += f4; col[5] += f5; col[6] += f6; col[7] += f7;
        }
#pragma unroll
        for (int r = 0; r < 8; ++r) {
            float v = rowv[r];
            v += __shfl_xor(v, 1); v += __shfl_xor(v, 2); v += __shfl_xor(v, 4);
            if (xb == 0) Rs[i * 64 + ys * 8 + r] = v;
        }
        float tot = 0.f;
#pragma unroll
        for (int j = 0; j < 8; ++j) {
            float c = col[j];
            c += __shfl_xor(c, 8); c += __shfl_xor(c, 16); c += __shfl_xor(c, 32);
            if (ys == 0) Cs[i * 64 + xb * 8 + j] = c;
            tot += c;
        }
        tot += __shfl_xor(tot, 1); tot += __shfl_xor(tot, 2); tot += __shfl_xor(tot, 4);
        if (l == 0) Ti[i] = tot;
    }
    __syncthreads();

    // ---------------- Phase 3: gate matmul (8x8) + sigmoid (t<512) ----------
    if (t < 512) {
        const int o = t >> 6, p = t & 63;
        float vy = b1[o], vx = b1[o];
#pragma unroll
        for (int i = 0; i < 8; ++i) {
            float wv = w1[o * 8 + i] * (1.0f / 64.0f);
            vy += wv * Rs[i * 64 + p];
            vx += wv * Cs[i * 64 + p];
        }
        sg[o * 128 + p] = sigm(vy);
        sg[o * 128 + 64 + p] = sigm(vx);
    }
    __syncthreads();

    // ---------------- Phase 4: instance-norm stats (t<512) ------------------
    if (t < 512) {
        const int i = t >> 6, l = t & 63, ys = l >> 3, xb = l & 7;
        const float4 sa = *reinterpret_cast<const float4*>(&sg[i * 128 + 64 + xb * 8]);
        const float4 sb = *reinterpret_cast<const float4*>(&sg[i * 128 + 64 + xb * 8 + 4]);
        float s = 0.f, s2 = 0.f;
#pragma unroll
        for (int r = 0; r < 8; ++r) {
            const float shv = sg[i * 128 + ys * 8 + r];
            const uint4 d = *reinterpret_cast<const uint4*>(
                &gxp[i * CSTR + (ys * 8 + r) * 32 + xb * 4]);
            float g0 = blo(d.x) * shv * sa.x; s += g0; s2 += g0 * g0;
            float g1 = bhi(d.x) * shv * sa.y; s += g1; s2 += g1 * g1;
            float g2 = blo(d.y) * shv * sa.z; s += g2; s2 += g2 * g2;
            float g3 = bhi(d.y) * shv * sa.w; s += g3; s2 += g3 * g3;
            float g4 = blo(d.z) * shv * sb.x; s += g4; s2 += g4 * g4;
            float g5 = bhi(d.z) * shv * sb.y; s += g5; s2 += g5 * g5;
            float g6 = blo(d.w) * shv * sb.z; s += g6; s2 += g6 * g6;
            float g7 = bhi(d.w) * shv * sb.w; s += g7; s2 += g7 * g7;
        }
#pragma unroll
        for (int off = 32; off; off >>= 1) {
            s += __shfl_xor(s, off);
            s2 += __shfl_xor(s2, off);
        }
        if (l == 0) {
            float mu = s * (1.0f / 4096.0f);
            float var = s2 * (1.0f / 4096.0f) - mu * mu;
            float a = rsqrtf(var + 1e-5f) * gn_w[i];
            Ai[i] = a;
            Ci[i] = gn_b[i] - mu * a;
        }
    }
    // ---- Phase 5a: conv channel means from rectangle sums (wave 0) ---------
    if (t < 64) {
        const int o = t >> 3, i = t & 7;
        const float T = Ti[i];
        float part = 0.f;
#pragma unroll
        for (int ky = 0; ky < 3; ++ky) {
            int dy = ky - 1;
#pragma unroll
            for (int kx = 0; kx < 3; ++kx) {
                int dx = kx - 1;
                float S = T;
                int er = (dy < 0) ? 63 : 0;
                int ec = (dx < 0) ? 63 : 0;
                if (dy != 0) S -= Rs[i * 64 + er];
                if (dx != 0) S -= Cs[i * 64 + ec];
                if (dy != 0 && dx != 0) {
                    uint u = gxp[i * CSTR + er * 32 + (ec >> 1)];
                    S += (ec & 1) ? bhi(u) : blo(u);
                }
                part += w3[((o * 8 + i) * 3 + ky) * 3 + kx] * S;
            }
        }
        part += __shfl_xor(part, 1); part += __shfl_xor(part, 2); part += __shfl_xor(part, 4);
        if (i == 0) m2s[o] = part * (1.0f / 4096.0f) + b3[o];
    }
    // ---- Phase 5b: the two 8-way softmaxes (same wave as 5a writers) -------
    if (t < 8) {
        float mx = m2s[0];
#pragma unroll
        for (int o = 1; o < 8; ++o) mx = fmaxf(mx, m2s[o]);
        float sum = 0.f;
#pragma unroll
        for (int o = 0; o < 8; ++o) sum += __expf(m2s[o] - mx);
        x21s[t] = __expf(m2s[t] - mx) / sum;
        // x1 spatial mean == gn_b exactly (normalized field)
        float mx1 = gn_b[0];
#pragma unroll
        for (int o = 1; o < 8; ++o) mx1 = fmaxf(mx1, gn_b[o]);
        float sum1 = 0.f;
#pragma unroll
        for (int o = 0; o < 8; ++o) sum1 += __expf(gn_b[o] - mx1);
        x11s[t] = __expf(gn_b[t] - mx1) / sum1;
    }
    __syncthreads();

    // ---- Phase 5c: collapsed filter (padded [8][12]), t1, constants --------
    if (t < 72) {
        const int i = t / 9, k = t % 9;
        float acc = 0.f;
#pragma unroll
        for (int o = 0; o < 8; ++o) acc += x11s[o] * w3[(o * 8 + i) * 9 + k];
        weff[i * 12 + (k / 3) * 4 + (k % 3)] = acc;
    }
    if (t < 512) {
        const int i = t >> 6, y = t & 63;
        t1s[i * 64 + y] = x21s[i] * Ai[i] * sg[i * 128 + y];
    }
    if (t == 0) {
        float wc = 0.f;
#pragma unroll
        for (int o = 0; o < 8; ++o) wc += x11s[o] * b3[o] + x21s[o] * Ci[o];
        wconst_s = wc;
    }
    __syncthreads();

    // ---- Phase 6: per-pixel weight, sigmoid, output (16 waves, 4 px) -------
    {
        const int y = t >> 4, xq = t & 15;      // 4 consecutive px per thread
        float ws0 = wconst_s, ws1 = wconst_s, ws2 = wconst_s, ws3 = wconst_s;
        uint2 ctr[8];
#pragma unroll
        for (int i = 0; i < 8; ++i) {
            const float t1v = t1s[i * 64 + y];
            const float4 sa = *reinterpret_cast<const float4*>(&sg[i * 128 + 64 + xq * 4]);
#pragma unroll
            for (int dy = -1; dy <= 1; ++dy) {
                const int yy = y + dy;
                if (yy < 0 || yy > 63) continue;   // edge rows only; shfl masked consistently
                const uint2 d = *reinterpret_cast<const uint2*>(
                    &gxp[i * CSTR + yy * 32 + xq * 2]);
                float f0 = blo(d.x), f1 = bhi(d.x), f2 = blo(d.y), f3 = bhi(d.y);
                float vm = __shfl_up(f3, 1);       // prev lane's last px (same row)
                float vp = __shfl_down(f0, 1);     // next lane's first px
                vm = (xq == 0) ? 0.f : vm;
                vp = (xq == 15) ? 0.f : vp;
                const float4 wv = *reinterpret_cast<const float4*>(&weff[i * 12 + (dy + 1) * 4]);
                ws0 += wv.x * vm + wv.y * f0 + wv.z * f1;
                ws1 += wv.x * f0 + wv.y * f1 + wv.z * f2;
                ws2 += wv.x * f1 + wv.y * f2 + wv.z * f3;
                ws3 += wv.x * f2 + wv.y * f3 + wv.z * vp;
                if (dy == 0) {
                    ctr[i] = d;
                    ws0 += t1v * sa.x * f0;
                    ws1 += t1v * sa.y * f1;
                    ws2 += t1v * sa.z * f2;
                    ws3 += t1v * sa.w * f3;
                }
            }
        }
        const float s0 = sigm(ws0), s1 = sigm(ws1), s2 = sigm(ws2), s3 = sigm(ws3);
        float4* out4 = reinterpret_cast<float4*>(out) + (size_t)b * 4096 * 64 + g * 2;
        const size_t p0 = (size_t)(y * 64 + xq * 4) * 64;
        float4 u, w;
        u.x = blo(ctr[0].x) * s0; u.y = blo(ctr[1].x) * s0; u.z = blo(ctr[2].x) * s0; u.w = blo(ctr[3].x) * s0;
        w.x = blo(ctr[4].x) * s0; w.y = blo(ctr[5].x) * s0; w.z = blo(ctr[6].x) * s0; w.w = blo(ctr[7].x) * s0;
        out4[p0 + 0] = u; out4[p0 + 1] = w;
        u.x = bhi(ctr[0].x) * s1; u.y = bhi(ctr[1].x) * s1; u.z = bhi(ctr[2].x) * s1; u.w = bhi(ctr[3].x) * s1;
        w.x = bhi(ctr[4].x) * s1; w.y = bhi(ctr[5].x) * s1; w.z = bhi(ctr[6].x) * s1; w.w = bhi(ctr[7].x) * s1;
        out4[p0 + 64] = u; out4[p0 + 65] = w;
        u.x = blo(ctr[0].y) * s2; u.y = blo(ctr[1].y) * s2; u.z = blo(ctr[2].y) * s2; u.w = blo(ctr[3].y) * s2;
        w.x = blo(ctr[4].y) * s2; w.y = blo(ctr[5].y) * s2; w.z = blo(ctr[6].y) * s2; w.w = blo(ctr[7].y) * s2;
        out4[p0 + 128] = u; out4[p0 + 129] = w;
        u.x = bhi(ctr[0].y) * s3; u.y = bhi(ctr[1].y) * s3; u.z = bhi(ctr[2].y) * s3; u.w = bhi(ctr[3].y) * s3;
        w.x = bhi(ctr[4].y) * s3; w.y = bhi(ctr[5].y) * s3; w.z = bhi(ctr[6].y) * s3; w.w = bhi(ctr[7].y) * s3;
        out4[p0 + 192] = u; out4[p0 + 193] = w;
    }
}

extern "C" void kernel_launch(void* const* d_in, const int* in_sizes, int n_in,
                              void* d_out, int out_size, void* d_ws, size_t ws_size,
                              hipStream_t stream) {
    const float* x    = (const float*)d_in[0];
    const float* w1   = (const float*)d_in[1];
    const float* b1   = (const float*)d_in[2];
    const float* w3   = (const float*)d_in[3];
    const float* b3   = (const float*)d_in[4];
    const float* gn_w = (const float*)d_in[5];
    const float* gn_b = (const float*)d_in[6];
    float* out = (float*)d_out;

    hipLaunchKernelGGL(fused_ema_kernel, dim3(NBLK), dim3(NTHR), 0, stream,
                       x, w1, b1, w3, b3, gn_w, gn_b, out);
}